// Round 1
// baseline (2970.820 us; speedup 1.0000x reference)
//
#include <hip/hip_runtime.h>

#define N_PTS  16384
#define B_SZ   8
#define NGROUP 1024
#define KNN_K  32
#define ATTR   7

// d_out layout (floats), reference return order:
// neighborhood (8,1024,32,7), center_idx (8,1024), centroids_attrs (8,1024,7), centroids_coors (8,1024,3)
#define OFF_NB     0
#define OFF_IDX    (B_SZ * NGROUP * KNN_K * ATTR)            // 1835008
#define OFF_CATTR  (OFF_IDX + B_SZ * NGROUP)                 // 1843200
#define OFF_CCOORD (OFF_CATTR + B_SZ * NGROUP * ATTR)        // 1900544

__device__ __forceinline__ bool argmax_wins(float dc, int ic, float db, int ib) {
    // challenger (dc,ic) beats incumbent (db,ib) for np.argmax (first max wins)
    return (dc > db) || ((dc == db) && (ic < ib));
}

// ---------------------------------------------------------------------------
// Kernel 0: x2[b][n] = sum_a xyz[b][n][a]^2, sequential order, no FMA
// ---------------------------------------------------------------------------
__global__ void x2_kernel(const float* __restrict__ xyz, float* __restrict__ x2) {
#pragma clang fp contract(off)
    int i = blockIdx.x * blockDim.x + threadIdx.x;
    if (i >= B_SZ * N_PTS) return;
    const float* q = xyz + (size_t)i * ATTR;
    float s = q[0] * q[0];
    s = s + q[1] * q[1];
    s = s + q[2] * q[2];
    s = s + q[3] * q[3];
    s = s + q[4] * q[4];
    s = s + q[5] * q[5];
    s = s + q[6] * q[6];
    x2[i] = s;
}

// ---------------------------------------------------------------------------
// Kernel 1: farthest point sampling. One block per batch, 1024 threads,
// 16 points per thread (strided: p = t + i*1024) held in registers.
// ---------------------------------------------------------------------------
__global__ __launch_bounds__(1024) void fps_kernel(const float* __restrict__ xyz,
                                                   float* __restrict__ out) {
#pragma clang fp contract(off)
    const int b = blockIdx.x;
    const int t = threadIdx.x;
    const int wave = t >> 6;
    const int lane = t & 63;
    const float* X = xyz + (size_t)b * N_PTS * ATTR;

    float px[16], py[16], pz[16], pd[16];
#pragma unroll
    for (int i = 0; i < 16; ++i) {
        const int p = t + (i << 10);
        const float* q = X + (size_t)p * ATTR;
        px[i] = q[0]; py[i] = q[1]; pz[i] = q[2];
        pd[i] = 1e10f;
    }

    __shared__ float bc[3];
    __shared__ int   sel[NGROUP];
    __shared__ float part_d[16];
    __shared__ int   part_i[16];

    if (t == 0) { bc[0] = px[0]; bc[1] = py[0]; bc[2] = pz[0]; sel[0] = 0; }
    __syncthreads();
    float cx = bc[0], cy = bc[1], cz = bc[2];

    for (int s = 0; s < NGROUP - 1; ++s) {
        // update distances + thread-local argmax (ties -> lowest index)
        float best = -1.0f;
        int   bidx = 0x7fffffff;
#pragma unroll
        for (int i = 0; i < 16; ++i) {
            const int p = t + (i << 10);
            float dx = px[i] - cx;
            float dy = py[i] - cy;
            float dz = pz[i] - cz;
            float dd = dx * dx + dy * dy;   // (dx^2 + dy^2)
            dd = dd + dz * dz;              // + dz^2, sequential, unfused
            float nd = fminf(pd[i], dd);
            pd[i] = nd;
            if (argmax_wins(nd, p, best, bidx)) { best = nd; bidx = p; }
        }
        // wave butterfly argmax
#pragma unroll
        for (int off = 1; off < 64; off <<= 1) {
            float od = __shfl_xor(best, off);
            int   oi = __shfl_xor(bidx, off);
            if (argmax_wins(od, oi, best, bidx)) { best = od; bidx = oi; }
        }
        if (lane == 0) { part_d[wave] = best; part_i[wave] = bidx; }
        __syncthreads();
        // every wave redundantly reduces the 16 partials -> uniform winner
        {
            int l = lane & 15;
            float d2 = part_d[l];
            int   i2 = part_i[l];
#pragma unroll
            for (int off = 1; off < 16; off <<= 1) {
                float od = __shfl_xor(d2, off);
                int   oi = __shfl_xor(i2, off);
                if (argmax_wins(od, oi, d2, i2)) { d2 = od; i2 = oi; }
            }
            bidx = __builtin_amdgcn_readfirstlane(i2);
        }
        // owner publishes winner coords (unrolled select avoids scratch)
        if (t == (bidx & 1023)) {
            const int slot = bidx >> 10;
            float sx = px[0], sy = py[0], sz = pz[0];
#pragma unroll
            for (int i = 1; i < 16; ++i)
                if (slot == i) { sx = px[i]; sy = py[i]; sz = pz[i]; }
            bc[0] = sx; bc[1] = sy; bc[2] = sz;
            sel[s + 1] = bidx;
        }
        __syncthreads();
        cx = bc[0]; cy = bc[1]; cz = bc[2];
    }

    // outputs: center_idx, centroids_attrs, centroids_coors
    {
        const int g = t;           // exactly 1024 threads
        const int idx = sel[g];
        const float* q = X + (size_t)idx * ATTR;
        float a0 = q[0], a1 = q[1], a2 = q[2], a3 = q[3], a4 = q[4], a5 = q[5], a6 = q[6];
        out[OFF_IDX + b * NGROUP + g] = (float)idx;
        float* ca = out + OFF_CATTR + (size_t)(b * NGROUP + g) * ATTR;
        ca[0] = a0; ca[1] = a1; ca[2] = a2; ca[3] = a3; ca[4] = a4; ca[5] = a5; ca[6] = a6;
        float* cc = out + OFF_CCOORD + (size_t)(b * NGROUP + g) * 3;
        cc[0] = a0; cc[1] = a1; cc[2] = a2;
    }
}

// ---------------------------------------------------------------------------
// Kernel 2: 32-NN in 7-D + gather/recenter. One wave per group; the sorted
// top-32 list lives distributed across lanes 0..31 (one slot per lane).
// d2 = (c2 + x2) - 2*dot, all sums sequential & unfused to match numpy.
// ---------------------------------------------------------------------------
__global__ __launch_bounds__(256) void knn_kernel(const float* __restrict__ xyz,
                                                  const float* __restrict__ x2,
                                                  float* __restrict__ out) {
#pragma clang fp contract(off)
    const int lane = threadIdx.x & 63;
    const int gg = blockIdx.x * 4 + (threadIdx.x >> 6);   // global group 0..8191
    const int b  = gg >> 10;
    const float* X   = xyz + (size_t)b * N_PTS * ATTR;
    const float* X2B = (x2 != nullptr) ? (x2 + (size_t)b * N_PTS) : nullptr;

    // center attrs (uniform across wave)
    const float* C = out + OFF_CATTR + (size_t)gg * ATTR;
    const float c0 = C[0], c1 = C[1], c2a = C[2], c3 = C[3], c4 = C[4], c5 = C[5], c6 = C[6];
    float csq = c0 * c0;
    csq = csq + c1 * c1;
    csq = csq + c2a * c2a;
    csq = csq + c3 * c3;
    csq = csq + c4 * c4;
    csq = csq + c5 * c5;
    csq = csq + c6 * c6;

    // distributed sorted list: lane j (<32) holds rank-j (ascending by (d2,idx))
    float ld = __builtin_inff();
    int   li = 0x7fffffff;
    float kd = __builtin_inff();   // current 32nd-best
    int   ki = 0x7fffffff;

    for (int p0 = 0; p0 < N_PTS; p0 += 64) {
        const int p = p0 + lane;
        const float* q = X + (size_t)p * ATTR;
        float dot = c0 * q[0];
        dot = dot + c1 * q[1];
        dot = dot + c2a * q[2];
        dot = dot + c3 * q[3];
        dot = dot + c4 * q[4];
        dot = dot + c5 * q[5];
        dot = dot + c6 * q[6];
        float xx;
        if (X2B != nullptr) {
            xx = X2B[p];
        } else {
            xx = q[0] * q[0];
            xx = xx + q[1] * q[1];
            xx = xx + q[2] * q[2];
            xx = xx + q[3] * q[3];
            xx = xx + q[4] * q[4];
            xx = xx + q[5] * q[5];
            xx = xx + q[6] * q[6];
        }
        const float d2 = (csq + xx) - 2.0f * dot;

        const bool cand = (d2 < kd) || (d2 == kd && p < ki);
        unsigned long long mask = __ballot(cand);
        while (mask) {
            const int l = __ffsll(mask) - 1;
            mask &= mask - 1;
            const float dc = __shfl(d2, l);
            const int   pc = __shfl(p, l);
            if ((dc < kd) || (dc == kd && pc < ki)) {
                // element ranks strictly before candidate?
                const bool before = (ld < dc) || (ld == dc && li < pc);
                const int pos = (int)__popcll(__ballot(before));
                const float sd = __shfl_up(ld, 1);
                const int   si = __shfl_up(li, 1);
                if (lane == pos)      { ld = dc; li = pc; }
                else if (lane > pos)  { ld = sd; li = si; }
                if (lane >= KNN_K)    { ld = __builtin_inff(); li = 0x7fffffff; }
                kd = __shfl(ld, KNN_K - 1);
                ki = __shfl(li, KNN_K - 1);
            }
        }
    }

    // neighborhood output: lane j writes rank-j neighbor (ascending d2)
    if (lane < KNN_K) {
        const float* q = X + (size_t)li * ATTR;
        float* o = out + OFF_NB + ((size_t)gg * KNN_K + lane) * ATTR;
        o[0] = q[0] - c0;
        o[1] = q[1] - c1;
        o[2] = q[2] - c2a;
        o[3] = q[3];
        o[4] = q[4];
        o[5] = q[5];
        o[6] = q[6];
    }
}

extern "C" void kernel_launch(void* const* d_in, const int* in_sizes, int n_in,
                              void* d_out, int out_size, void* d_ws, size_t ws_size,
                              hipStream_t stream) {
    const float* xyz = (const float*)d_in[0];
    float* out = (float*)d_out;

    const bool use_ws = ws_size >= (size_t)(B_SZ * N_PTS) * sizeof(float);
    float* x2 = use_ws ? (float*)d_ws : nullptr;

    if (use_ws) {
        x2_kernel<<<(B_SZ * N_PTS + 255) / 256, 256, 0, stream>>>(xyz, x2);
    }
    fps_kernel<<<B_SZ, 1024, 0, stream>>>(xyz, out);
    knn_kernel<<<(B_SZ * NGROUP) / 4, 256, 0, stream>>>(xyz, x2, out);
}

// Round 2
// 2197.696 us; speedup vs baseline: 1.3518x; 1.3518x over previous
//
#include <hip/hip_runtime.h>

#define N_PTS  16384
#define B_SZ   8
#define NGROUP 1024
#define KNN_K  32
#define ATTR   7

// d_out layout (floats), reference return order:
// neighborhood (8,1024,32,7), center_idx (8,1024), centroids_attrs (8,1024,7), centroids_coors (8,1024,3)
#define OFF_NB     0
#define OFF_IDX    (B_SZ * NGROUP * KNN_K * ATTR)            // 1835008
#define OFF_CATTR  (OFF_IDX + B_SZ * NGROUP)                 // 1843200
#define OFF_CCOORD (OFF_CATTR + B_SZ * NGROUP * ATTR)        // 1900544

typedef float v2f __attribute__((ext_vector_type(2)));                 // packed-f32 math
typedef float f2u __attribute__((ext_vector_type(2), aligned(4)));     // 4B-aligned vec load

// ---------------------------------------------------------------------------
// Kernel 0: prep — x2[b][n] = sum_a xyz[b][n][a]^2 (sequential, no FMA) and
// SoA transpose xt[b][a][n] for coalesced KNN reads.
// ---------------------------------------------------------------------------
__global__ void prep_kernel(const float* __restrict__ xyz, float* __restrict__ x2,
                            float* __restrict__ xt) {
#pragma clang fp contract(off)
    int i = blockIdx.x * blockDim.x + threadIdx.x;
    if (i >= B_SZ * N_PTS) return;
    const int b = i >> 14;
    const int p = i & (N_PTS - 1);
    const float* q = xyz + (size_t)i * ATTR;
    f2u a01 = *(const f2u*)q;
    f2u a23 = *(const f2u*)(q + 2);
    f2u a45 = *(const f2u*)(q + 4);
    float a6 = q[6];
    float s = a01.x * a01.x;
    s = s + a01.y * a01.y;
    s = s + a23.x * a23.x;
    s = s + a23.y * a23.y;
    s = s + a45.x * a45.x;
    s = s + a45.y * a45.y;
    s = s + a6 * a6;
    x2[i] = s;
    float* T = xt + (size_t)b * ATTR * N_PTS + p;
    T[0 * N_PTS] = a01.x;
    T[1 * N_PTS] = a01.y;
    T[2 * N_PTS] = a23.x;
    T[3 * N_PTS] = a23.y;
    T[4 * N_PTS] = a45.x;
    T[5 * N_PTS] = a45.y;
    T[6 * N_PTS] = a6;
}

// ---------------------------------------------------------------------------
// Kernel 1: farthest point sampling. One 1024-thread block per batch,
// 16 points/thread in registers as float2 pairs (packed v_pk_* fp32 math).
// Per step: ONE barrier. Reduction via monotone u64 key (d-bits<<32 |
// (16384-idx)) -> wave butterfly max -> lane-0 atomicMax into a
// triple-buffered LDS slot (reset is barrier-ordered) -> broadcast read.
// Winner coords re-fetched via uniform (scalar) global load — no 2nd barrier.
// ---------------------------------------------------------------------------
__global__ __launch_bounds__(1024) void fps_kernel(const float* __restrict__ xyz,
                                                   float* __restrict__ out) {
#pragma clang fp contract(off)
    const int b = blockIdx.x;
    const int t = threadIdx.x;
    const int lane = t & 63;
    const float* X = xyz + (size_t)b * N_PTS * ATTR;

    v2f px[8], py[8], pz[8], pd[8];
#pragma unroll
    for (int j = 0; j < 8; ++j) {
        const int p0 = t + (j << 11);              // t + (2j)*1024
        const float* q0 = X + (size_t)p0 * ATTR;
        const float* q1 = q0 + (size_t)1024 * ATTR;
        f2u u0 = *(const f2u*)q0; float z0 = q0[2];
        f2u u1 = *(const f2u*)q1; float z1 = q1[2];
        px[j] = (v2f){u0.x, u1.x};
        py[j] = (v2f){u0.y, u1.y};
        pz[j] = (v2f){z0, z1};
        pd[j] = (v2f){1e10f, 1e10f};
    }

    __shared__ unsigned long long slot[3];
    __shared__ int sel[NGROUP];
    if (t == 0) { slot[0] = 0ull; sel[0] = 0; }
    float cx = X[0], cy = X[1], cz = X[2];        // farthest=0 initial centroid
    __syncthreads();

    for (int s = 0; s < NGROUP - 1; ++s) {
        const v2f cx2 = {cx, cx}, cy2 = {cy, cy}, cz2 = {cz, cz};
        // update distances + thread-local argmax.
        // strict '>' with ascending point index == np.argmax first-max-wins.
        float best = -1.0f;
        int   bidx = 0;
#pragma unroll
        for (int j = 0; j < 8; ++j) {
            v2f dx = px[j] - cx2;                 // v_pk_add (neg)
            v2f dy = py[j] - cy2;
            v2f dz = pz[j] - cz2;
            v2f a  = dx * dx;                     // v_pk_mul
            a = a + dy * dy;                      // (dx^2+dy^2) — unfused
            a = a + dz * dz;                      // + dz^2 — sequential
            v2f nd;
            nd.x = fminf(pd[j].x, a.x);
            nd.y = fminf(pd[j].y, a.y);
            pd[j] = nd;
            if (nd.x > best) { best = nd.x; bidx = t + ((2 * j) << 10); }
            if (nd.y > best) { best = nd.y; bidx = t + ((2 * j + 1) << 10); }
        }
        // monotone key: larger d wins; tie -> smaller index (larger 16384-idx).
        // d >= 0 always, so float bits are order-preserving as u32.
        unsigned long long key =
            ((unsigned long long)__float_as_uint(best) << 32) |
            (unsigned)(N_PTS - bidx);
#pragma unroll
        for (int off = 1; off < 64; off <<= 1) {
            unsigned long long ok = __shfl_xor(key, off);
            if (ok > key) key = ok;
        }
        if (lane == 0) atomicMax(&slot[s % 3], key);
        // reset the NEXT step's slot now: reads of this slot happened at step
        // s-2 (before barrier s-1); next step's atomics happen after barrier s.
        if (t == 0) slot[(s + 1) % 3] = 0ull;
        __syncthreads();
        key = slot[s % 3];
        const int lo = (int)(unsigned)key;
        bidx = N_PTS - __builtin_amdgcn_readfirstlane(lo);
        if (t == 0) sel[s + 1] = bidx;
        // uniform (SGPR) address -> scalar load of winner coords, L2-hit.
        const float* q = X + (size_t)bidx * ATTR;
        cx = q[0]; cy = q[1]; cz = q[2];
    }
    __syncthreads();

    // outputs: center_idx, centroids_attrs, centroids_coors (1024 threads = 1024 groups)
    {
        const int g = t;
        const int idx = sel[g];
        const float* q = X + (size_t)idx * ATTR;
        float a0 = q[0], a1 = q[1], a2 = q[2], a3 = q[3], a4 = q[4], a5 = q[5], a6 = q[6];
        out[OFF_IDX + b * NGROUP + g] = (float)idx;
        float* ca = out + OFF_CATTR + (size_t)(b * NGROUP + g) * ATTR;
        ca[0] = a0; ca[1] = a1; ca[2] = a2; ca[3] = a3; ca[4] = a4; ca[5] = a5; ca[6] = a6;
        float* cc = out + OFF_CCOORD + (size_t)(b * NGROUP + g) * 3;
        cc[0] = a0; cc[1] = a1; cc[2] = a2;
    }
}

// ---------------------------------------------------------------------------
// distributed top-32 insert (sorted list lives one-slot-per-lane, lanes 0..31)
// ---------------------------------------------------------------------------
__device__ __forceinline__ void topk_insert(float d2, int p, int lane,
                                            float& ld, int& li, float& kd, int& ki) {
    const bool cand = (d2 < kd) || (d2 == kd && p < ki);
    unsigned long long mask = __ballot(cand);
    while (mask) {
        const int l = __ffsll(mask) - 1;
        mask &= mask - 1;
        const float dc = __shfl(d2, l);
        const int   pc = __shfl(p, l);
        if ((dc < kd) || (dc == kd && pc < ki)) {
            const bool before = (ld < dc) || (ld == dc && li < pc);
            const int pos = (int)__popcll(__ballot(before));
            const float sd = __shfl_up(ld, 1);
            const int   si = __shfl_up(li, 1);
            if (lane == pos)      { ld = dc; li = pc; }
            else if (lane > pos)  { ld = sd; li = si; }
            if (lane >= KNN_K)    { ld = __builtin_inff(); li = 0x7fffffff; }
            kd = __shfl(ld, KNN_K - 1);
            ki = __shfl(li, KNN_K - 1);
        }
    }
}

// ---------------------------------------------------------------------------
// Kernel 2: 32-NN in 7-D + gather/recenter. One wave per group.
// SoA path: 7+1 coalesced dword loads per 64-point batch (28 line-touches
// vs 196 for AoS). d2 = (c2 + x2) - 2*dot, sums sequential & unfused.
// ---------------------------------------------------------------------------
__global__ __launch_bounds__(256) void knn_kernel(const float* __restrict__ xyz,
                                                  const float* __restrict__ x2,
                                                  const float* __restrict__ xt,
                                                  float* __restrict__ out) {
#pragma clang fp contract(off)
    const int lane = threadIdx.x & 63;
    const int gg = blockIdx.x * 4 + (threadIdx.x >> 6);   // global group 0..8191
    const int b  = gg >> 10;
    const float* X = xyz + (size_t)b * N_PTS * ATTR;

    const float* C = out + OFF_CATTR + (size_t)gg * ATTR;
    const float c0 = C[0], c1 = C[1], c2a = C[2], c3 = C[3], c4 = C[4], c5 = C[5], c6 = C[6];
    float csq = c0 * c0;
    csq = csq + c1 * c1;
    csq = csq + c2a * c2a;
    csq = csq + c3 * c3;
    csq = csq + c4 * c4;
    csq = csq + c5 * c5;
    csq = csq + c6 * c6;

    float ld = __builtin_inff();
    int   li = 0x7fffffff;
    float kd = __builtin_inff();
    int   ki = 0x7fffffff;

    if (xt != nullptr) {
        const float* T0 = xt + (size_t)b * ATTR * N_PTS;
        const float* T1 = T0 + N_PTS;
        const float* T2 = T1 + N_PTS;
        const float* T3 = T2 + N_PTS;
        const float* T4 = T3 + N_PTS;
        const float* T5 = T4 + N_PTS;
        const float* T6 = T5 + N_PTS;
        const float* XB = x2 + (size_t)b * N_PTS;
        for (int p0 = 0; p0 < N_PTS; p0 += 64) {
            const int p = p0 + lane;
            const float q0 = T0[p], q1 = T1[p], q2 = T2[p], q3 = T3[p];
            const float q4 = T4[p], q5 = T5[p], q6 = T6[p];
            float dot = c0 * q0;
            dot = dot + c1 * q1;
            dot = dot + c2a * q2;
            dot = dot + c3 * q3;
            dot = dot + c4 * q4;
            dot = dot + c5 * q5;
            dot = dot + c6 * q6;
            const float xx = XB[p];
            const float d2 = (csq + xx) - 2.0f * dot;
            topk_insert(d2, p, lane, ld, li, kd, ki);
        }
    } else {
        for (int p0 = 0; p0 < N_PTS; p0 += 64) {
            const int p = p0 + lane;
            const float* q = X + (size_t)p * ATTR;
            float dot = c0 * q[0];
            dot = dot + c1 * q[1];
            dot = dot + c2a * q[2];
            dot = dot + c3 * q[3];
            dot = dot + c4 * q[4];
            dot = dot + c5 * q[5];
            dot = dot + c6 * q[6];
            float xx = q[0] * q[0];
            xx = xx + q[1] * q[1];
            xx = xx + q[2] * q[2];
            xx = xx + q[3] * q[3];
            xx = xx + q[4] * q[4];
            xx = xx + q[5] * q[5];
            xx = xx + q[6] * q[6];
            const float d2 = (csq + xx) - 2.0f * dot;
            topk_insert(d2, p, lane, ld, li, kd, ki);
        }
    }

    // neighborhood output: lane j writes rank-j neighbor (ascending (d2,idx))
    if (lane < KNN_K) {
        const float* q = X + (size_t)li * ATTR;
        float* o = out + OFF_NB + ((size_t)gg * KNN_K + lane) * ATTR;
        o[0] = q[0] - c0;
        o[1] = q[1] - c1;
        o[2] = q[2] - c2a;
        o[3] = q[3];
        o[4] = q[4];
        o[5] = q[5];
        o[6] = q[6];
    }
}

extern "C" void kernel_launch(void* const* d_in, const int* in_sizes, int n_in,
                              void* d_out, int out_size, void* d_ws, size_t ws_size,
                              hipStream_t stream) {
    const float* xyz = (const float*)d_in[0];
    float* out = (float*)d_out;

    const size_t need = (size_t)(B_SZ * N_PTS) * (1 + ATTR) * sizeof(float);  // 4 MiB
    const bool use_ws = ws_size >= need;
    float* x2 = use_ws ? (float*)d_ws : nullptr;
    float* xt = use_ws ? ((float*)d_ws + B_SZ * N_PTS) : nullptr;

    if (use_ws) {
        prep_kernel<<<(B_SZ * N_PTS + 255) / 256, 256, 0, stream>>>(xyz, x2, xt);
    }
    fps_kernel<<<B_SZ, 1024, 0, stream>>>(xyz, out);
    knn_kernel<<<(B_SZ * NGROUP) / 4, 256, 0, stream>>>(xyz, x2, xt, out);
}